// Round 1
// baseline (3605.506 us; speedup 1.0000x reference)
//
#include <hip/hip_runtime.h>

#define BB 8
#define CI 128
#define CO 128
#define KK 3
#define SD 512
#define HH 256
#define WW 256

#define TSX 32
#define TSY 32
#define COB 8
#define CIB 4

// Static device scratch (avoids assumptions about ws_size).
__device__ float g_s[BB * CI];
__device__ float g_wt[BB * CO * CI * KK * KK];

__global__ void affine_kernel(const float* __restrict__ style,
                              const float* __restrict__ aff_w,
                              const float* __restrict__ aff_b) {
    int b = blockIdx.x;       // 0..7
    int ci = threadIdx.x;     // 0..127
    const float gain = 0.044194173824159216f;  // 1/sqrt(512)
    const float* st = style + b * SD;
    const float* aw = aff_w + ci * SD;
    float acc = 0.f;
    #pragma unroll 8
    for (int j = 0; j < SD; ++j) acc += st[j] * aw[j];
    g_s[b * CI + ci] = acc * gain + aff_b[ci];
}

__global__ __launch_bounds__(256) void modulate_kernel(const float* __restrict__ w_base) {
    int blk = blockIdx.x;           // 0..B*CO-1
    int b = blk / CO, co = blk % CO;
    int tid = threadIdx.x;          // 256 threads
    const float wgain = 0.029462782549439483f;  // 1/sqrt(128*9)
    const int n = CI * KK * KK;     // 1152
    const float* wb = w_base + co * n;
    const float* sp = g_s + b * CI;

    float v[5];
    float sq = 0.f;
    #pragma unroll
    for (int i = 0; i < 5; ++i) {
        int idx = tid + i * 256;
        float w = 0.f;
        if (idx < n) {
            int ci = idx / 9;
            w = wb[idx] * wgain * sp[ci];
        }
        v[i] = w;
        sq += w * w;
    }
    // wave reduce
    #pragma unroll
    for (int off = 32; off > 0; off >>= 1) sq += __shfl_down(sq, off, 64);
    __shared__ float red[4];
    int lane = tid & 63, wv = tid >> 6;
    if (lane == 0) red[wv] = sq;
    __syncthreads();
    float tot = red[0] + red[1] + red[2] + red[3];
    float d = rsqrtf(tot + 1e-8f);
    float* outp = g_wt + (size_t)blk * n;
    #pragma unroll
    for (int i = 0; i < 5; ++i) {
        int idx = tid + i * 256;
        if (idx < n) outp[idx] = v[i] * d;
    }
}

__global__ __launch_bounds__(256) void conv_kernel(const float* __restrict__ x,
                                                   float* __restrict__ y) {
    // grid: (HW tiles = 64, CO/COB = 16, B = 8)
    const int b = blockIdx.z;
    const int cog = blockIdx.y;
    const int tile = blockIdx.x;
    const int ntx = WW / TSX;                 // 8
    const int tx0 = (tile % ntx) * TSX;
    const int ty0 = (tile / ntx) * TSY;
    const int tid = threadIdx.x;
    const int px = (tid & 15) * 2;            // 0..30 step 2
    const int py = (tid >> 4) * 2;            // 0..30 step 2

    __shared__ float xs[CIB][TSY + 2][TSX + 2];   // 4*34*34 floats
    __shared__ float ws[COB][CIB][9];

    float acc[COB][4];
    #pragma unroll
    for (int c = 0; c < COB; ++c)
        #pragma unroll
        for (int p = 0; p < 4; ++p) acc[c][p] = 0.f;

    const float* wt_base = g_wt + ((size_t)(b * CO + cog * COB)) * (CI * 9);

    for (int cc = 0; cc < CI; cc += CIB) {
        __syncthreads();
        // stage x tile (with halo, zero-padded at borders)
        for (int i = tid; i < CIB * 34 * 34; i += 256) {
            int ci = i / (34 * 34);
            int rem = i % (34 * 34);
            int r = rem / 34;
            int c = rem % 34;
            int gy = ty0 + r - 1;
            int gx = tx0 + c - 1;
            float v = 0.f;
            if (gy >= 0 && gy < HH && gx >= 0 && gx < WW)
                v = x[(((size_t)(b * CI + cc + ci)) * HH + gy) * WW + gx];
            xs[ci][r][c] = v;
        }
        // stage weights for this (co-group, ci-chunk)
        for (int i = tid; i < COB * CIB * 9; i += 256) {
            int co = i / (CIB * 9);
            int rem = i % (CIB * 9);
            int ci = rem / 9;
            int kk = rem % 9;
            ws[co][ci][kk] = wt_base[(size_t)(co * CI + cc + ci) * 9 + kk];
        }
        __syncthreads();

        #pragma unroll
        for (int ci = 0; ci < CIB; ++ci) {
            float xv[4][4];
            #pragma unroll
            for (int r = 0; r < 4; ++r)
                #pragma unroll
                for (int c = 0; c < 4; ++c)
                    xv[r][c] = xs[ci][py + r][px + c];
            #pragma unroll
            for (int co = 0; co < COB; ++co) {
                float w0 = ws[co][ci][0], w1 = ws[co][ci][1], w2 = ws[co][ci][2];
                float w3 = ws[co][ci][3], w4 = ws[co][ci][4], w5 = ws[co][ci][5];
                float w6 = ws[co][ci][6], w7 = ws[co][ci][7], w8 = ws[co][ci][8];
                #pragma unroll
                for (int pr = 0; pr < 2; ++pr)
                    #pragma unroll
                    for (int pc = 0; pc < 2; ++pc) {
                        float a = acc[co][pr * 2 + pc];
                        a += w0 * xv[pr + 0][pc + 0];
                        a += w1 * xv[pr + 0][pc + 1];
                        a += w2 * xv[pr + 0][pc + 2];
                        a += w3 * xv[pr + 1][pc + 0];
                        a += w4 * xv[pr + 1][pc + 1];
                        a += w5 * xv[pr + 1][pc + 2];
                        a += w6 * xv[pr + 2][pc + 0];
                        a += w7 * xv[pr + 2][pc + 1];
                        a += w8 * xv[pr + 2][pc + 2];
                        acc[co][pr * 2 + pc] = a;
                    }
            }
        }
    }

    // write 2x2 patch per co as float2 pairs
    #pragma unroll
    for (int co = 0; co < COB; ++co) {
        #pragma unroll
        for (int pr = 0; pr < 2; ++pr) {
            int oy = ty0 + py + pr;
            int ox = tx0 + px;
            float2 v2 = make_float2(acc[co][pr * 2 + 0], acc[co][pr * 2 + 1]);
            *reinterpret_cast<float2*>(
                &y[(((size_t)(b * CO + cog * COB + co)) * HH + oy) * WW + ox]) = v2;
        }
    }
}

extern "C" void kernel_launch(void* const* d_in, const int* in_sizes, int n_in,
                              void* d_out, int out_size, void* d_ws, size_t ws_size,
                              hipStream_t stream) {
    const float* x = (const float*)d_in[0];
    const float* style = (const float*)d_in[1];
    const float* w_base = (const float*)d_in[2];
    const float* aff_w = (const float*)d_in[3];
    const float* aff_b = (const float*)d_in[4];
    float* y = (float*)d_out;

    affine_kernel<<<BB, CI, 0, stream>>>(style, aff_w, aff_b);
    modulate_kernel<<<BB * CO, 256, 0, stream>>>(w_base);
    conv_kernel<<<dim3((HH / TSY) * (WW / TSX), CO / COB, BB), 256, 0, stream>>>(x, y);
}

// Round 2
// 545.842 us; speedup vs baseline: 6.6054x; 6.6054x over previous
//
#include <hip/hip_runtime.h>
#include <stdint.h>

#define BB 8
#define SD 512

typedef unsigned short u16;
typedef __attribute__((ext_vector_type(8))) __bf16 bf16x8;
typedef __attribute__((ext_vector_type(4))) float f32x4;

// Static device scratch
__device__ float g_s[BB * 128];
__device__ u16 g_wtb[BB * 9 * 2 * 8192];   // [b][tap][chunk][co][ci2] bf16 bits

__device__ __forceinline__ u16 f2bf(float f) {
    uint32_t u = __float_as_uint(f);
    u += 0x7FFFu + ((u >> 16) & 1u);   // RNE
    return (u16)(u >> 16);
}

__global__ void affine_kernel(const float* __restrict__ style,
                              const float* __restrict__ aff_w,
                              const float* __restrict__ aff_b) {
    int b = blockIdx.x;       // 0..7
    int ci = threadIdx.x;     // 0..127
    const float gain = 0.044194173824159216f;  // 1/sqrt(512)
    const float* st = style + b * SD;
    const float* aw = aff_w + ci * SD;
    float acc = 0.f;
    #pragma unroll 8
    for (int j = 0; j < SD; ++j) acc += st[j] * aw[j];
    g_s[b * 128 + ci] = acc * gain + aff_b[ci];
}

__global__ __launch_bounds__(256) void modulate_kernel(const float* __restrict__ w_base) {
    int blk = blockIdx.x;           // 0..B*CO-1
    int b = blk >> 7, co = blk & 127;
    int tid = threadIdx.x;
    const float wgain = 0.029462782549439483f;  // 1/sqrt(128*9)
    const int n = 1152;
    const float* wb = w_base + co * n;
    const float* sp = g_s + b * 128;

    float v[5];
    float sq = 0.f;
    #pragma unroll
    for (int i = 0; i < 5; ++i) {
        int idx = tid + i * 256;
        float w = 0.f;
        if (idx < n) {
            int ci = idx / 9;
            w = wb[idx] * wgain * sp[ci];
        }
        v[i] = w;
        sq += w * w;
    }
    #pragma unroll
    for (int off = 32; off > 0; off >>= 1) sq += __shfl_down(sq, off, 64);
    __shared__ float red[4];
    int lane = tid & 63, wvi = tid >> 6;
    if (lane == 0) red[wvi] = sq;
    __syncthreads();
    float tot = red[0] + red[1] + red[2] + red[3];
    float d = rsqrtf(tot + 1e-8f);
    #pragma unroll
    for (int i = 0; i < 5; ++i) {
        int idx = tid + i * 256;
        if (idx < n) {
            int ci = idx / 9;
            int k9 = idx - ci * 9;              // tap = ky*3+kx
            u16 hv = f2bf(v[i] * d);
            // dest: [b][tap][chunk][co][ci2]
            g_wtb[((size_t)(b * 9 + k9) * 2 + (ci >> 6)) * 8192 + co * 64 + (ci & 63)] = hv;
        }
    }
}

// Implicit-GEMM conv: per block: batch b, 8x16 pixel tile, all 128 co.
__global__ __launch_bounds__(256, 2) void conv_kernel(const float* __restrict__ x,
                                                      float* __restrict__ y) {
    __shared__ __align__(16) u16 xs[10 * 18 * 128];   // [pl][ci] swizzled, 46080 B
    __shared__ __align__(16) u16 a_lds[2][8192];      // [co][ci2] swizzled, 2x16 KB

    const int b = blockIdx.y;
    const int tile = blockIdx.x;          // 0..511
    const int ty = tile >> 4, tx = tile & 15;
    const int y0 = ty * 8, x0 = tx * 16;
    const int tid = threadIdx.x;
    const int lane = tid & 63, wv = tid >> 6;
    const int kgrp = lane >> 4, lp = lane & 15;
    const int coBase = (wv >> 1) * 64;    // wave co origin
    const int pb16 = (wv & 1) * 4;        // wave pixel-row origin (rows of 16 px)
    const int sw = (lp & 7) << 4;

    // ---- stage X tile (halo 10x18, all 128 ci), fp32 -> bf16, swizzled ----
    {
        const int g = tid >> 5, l32 = tid & 31;
        #pragma unroll
        for (int c8 = 0; c8 < 16; ++c8) {
            int ci = c8 * 8 + g;
            const float* xp = x + ((size_t)(b * 128 + ci)) * 65536;
            #pragma unroll
            for (int c = 0; c < 6; ++c) {
                int flat = c * 32 + l32;
                if (flat < 180) {
                    int yy = flat / 18;
                    int xx = flat - yy * 18;
                    int gy = y0 + yy - 1, gx = x0 + xx - 1;
                    float v = 0.f;
                    if ((unsigned)gy < 256u && (unsigned)gx < 256u) v = xp[gy * 256 + gx];
                    int byte = flat * 256 + ((ci * 2) ^ ((flat & 7) << 4));
                    *(u16*)((char*)xs + byte) = f2bf(v);
                }
            }
        }
    }

    // ---- stage A step 0 ----
    const u16* wtb = g_wtb + (size_t)b * 9 * 2 * 8192;
    {
        const uint4* src = (const uint4*)wtb;       // step 0
        #pragma unroll
        for (int it = 0; it < 4; ++it) {
            int q = it * 256 + tid;
            uint4 v = src[q];
            int co = q >> 3, g8 = q & 7;
            int byte = co * 128 + ((g8 * 16) ^ ((co & 7) << 4));
            *(uint4*)((char*)a_lds[0] + byte) = v;
        }
    }
    __syncthreads();

    f32x4 acc[4][4];
    #pragma unroll
    for (int mf = 0; mf < 4; ++mf)
        #pragma unroll
        for (int nf = 0; nf < 4; ++nf)
            acc[mf][nf] = (f32x4){0.f, 0.f, 0.f, 0.f};

    const char* xsb = (const char*)xs;

    for (int s = 0; s < 18; ++s) {
        const int cur = s & 1;
        const int tap = s >> 1, chunk = s & 1;
        const int ky = tap / 3, kx = tap - 3 * ky;

        // T14: issue next A-tile loads early
        uint4 stv[4];
        int dstb[4];
        if (s < 17) {
            const uint4* src = (const uint4*)(wtb + (size_t)(s + 1) * 8192);
            #pragma unroll
            for (int it = 0; it < 4; ++it) {
                int q = it * 256 + tid;
                stv[it] = src[q];
                int co = q >> 3, g8 = q & 7;
                dstb[it] = co * 128 + ((g8 * 16) ^ ((co & 7) << 4));
            }
        }

        // compute on buffer cur
        const char* ab = (const char*)a_lds[cur];
        const int cbb = chunk * 128;               // ci-chunk byte offset in xs rows
        #pragma unroll
        for (int ks = 0; ks < 2; ++ks) {
            const int kbA = (ks * 64 + kgrp * 16) ^ sw;   // co&7 == lp&7
            bf16x8 af[4];
            #pragma unroll
            for (int mf = 0; mf < 4; ++mf) {
                int co = coBase + mf * 16 + lp;
                af[mf] = *(const bf16x8*)(ab + co * 128 + kbA);
            }
            bf16x8 bfv[4];
            #pragma unroll
            for (int nf = 0; nf < 4; ++nf) {
                int pl = (pb16 + nf + ky) * 18 + lp + kx;
                int byte = pl * 256 + ((cbb + ks * 64 + kgrp * 16) ^ ((pl & 7) << 4));
                bfv[nf] = *(const bf16x8*)(xsb + byte);
            }
            #pragma unroll
            for (int mf = 0; mf < 4; ++mf)
                #pragma unroll
                for (int nf = 0; nf < 4; ++nf)
                    acc[mf][nf] = __builtin_amdgcn_mfma_f32_16x16x32_bf16(
                        af[mf], bfv[nf], acc[mf][nf], 0, 0, 0);
        }

        // write-late half of T14
        if (s < 17) {
            #pragma unroll
            for (int it = 0; it < 4; ++it)
                *(uint4*)((char*)a_lds[cur ^ 1] + dstb[it]) = stv[it];
        }
        __syncthreads();
    }

    // ---- epilogue: C = acc -> y ----
    float* yb = y + (size_t)b * 128 * 65536;
    #pragma unroll
    for (int mf = 0; mf < 4; ++mf) {
        #pragma unroll
        for (int nf = 0; nf < 4; ++nf) {
            int gy = y0 + pb16 + nf;
            #pragma unroll
            for (int r = 0; r < 4; ++r) {
                int co = coBase + mf * 16 + kgrp * 4 + r;
                yb[(size_t)co * 65536 + gy * 256 + x0 + lp] = acc[mf][nf][r];
            }
        }
    }
}

extern "C" void kernel_launch(void* const* d_in, const int* in_sizes, int n_in,
                              void* d_out, int out_size, void* d_ws, size_t ws_size,
                              hipStream_t stream) {
    const float* x = (const float*)d_in[0];
    const float* style = (const float*)d_in[1];
    const float* w_base = (const float*)d_in[2];
    const float* aff_w = (const float*)d_in[3];
    const float* aff_b = (const float*)d_in[4];
    float* y = (float*)d_out;

    affine_kernel<<<BB, 128, 0, stream>>>(style, aff_w, aff_b);
    modulate_kernel<<<BB * 128, 256, 0, stream>>>(w_base);
    conv_kernel<<<dim3(512, BB), 256, 0, stream>>>(x, y);
}

// Round 4
// 369.204 us; speedup vs baseline: 9.7656x; 1.4784x over previous
//
#include <hip/hip_runtime.h>
#include <stdint.h>

#define BB 8
#define SD 512

typedef unsigned short u16;
typedef __attribute__((ext_vector_type(8))) __bf16 bf16x8;
typedef __attribute__((ext_vector_type(4))) float f32x4;

// Static device scratch
__device__ float g_s[BB * 128];
__device__ u16 g_wtb[BB * 9 * 2 * 8192];                  // [b][tap][chunk]: 16KB blocks, swizzled
__device__ u16 g_xb[(size_t)BB * 258 * 258 * 128 + 2048]; // [b][gy_p][gx_p][ci] bf16, swizzled per pixel

typedef const __attribute__((address_space(1))) uint32_t* gp1;
typedef __attribute__((address_space(3))) uint32_t* lp3;

__device__ __forceinline__ void glds16(const void* g, void* l) {
    __builtin_amdgcn_global_load_lds((gp1)g, (lp3)l, 16, 0, 0);
}
__device__ __forceinline__ void glds4(const void* g, void* l) {
    __builtin_amdgcn_global_load_lds((gp1)g, (lp3)l, 4, 0, 0);
}

__device__ __forceinline__ u16 f2bf(float f) {
    uint32_t u = __float_as_uint(f);
    u += 0x7FFFu + ((u >> 16) & 1u);   // RNE
    return (u16)(u >> 16);
}

__global__ void affine_kernel(const float* __restrict__ style,
                              const float* __restrict__ aff_w,
                              const float* __restrict__ aff_b) {
    int b = blockIdx.x;
    int ci = threadIdx.x;
    const float gain = 0.044194173824159216f;  // 1/sqrt(512)
    const float* st = style + b * SD;
    const float* aw = aff_w + ci * SD;
    float acc = 0.f;
    #pragma unroll 8
    for (int j = 0; j < SD; ++j) acc += st[j] * aw[j];
    g_s[b * 128 + ci] = acc * gain + aff_b[ci];
}

__global__ __launch_bounds__(256) void modulate_kernel(const float* __restrict__ w_base) {
    int blk = blockIdx.x;           // 0..B*CO-1
    int b = blk >> 7, co = blk & 127;
    int tid = threadIdx.x;
    const float wgain = 0.029462782549439483f;  // 1/sqrt(128*9)
    const int n = 1152;
    const float* wb = w_base + co * n;
    const float* sp = g_s + b * 128;

    float v[5];
    float sq = 0.f;
    #pragma unroll
    for (int i = 0; i < 5; ++i) {
        int idx = tid + i * 256;
        float w = 0.f;
        if (idx < n) {
            int ci = idx / 9;
            w = wb[idx] * wgain * sp[ci];
        }
        v[i] = w;
        sq += w * w;
    }
    #pragma unroll
    for (int off = 32; off > 0; off >>= 1) sq += __shfl_down(sq, off, 64);
    __shared__ float red[4];
    int lane = tid & 63, wvi = tid >> 6;
    if (lane == 0) red[wvi] = sq;
    __syncthreads();
    float tot = red[0] + red[1] + red[2] + red[3];
    float d = rsqrtf(tot + 1e-8f);
    #pragma unroll
    for (int i = 0; i < 5; ++i) {
        int idx = tid + i * 256;
        if (idx < n) {
            int ci = idx / 9;
            int k9 = idx - ci * 9;              // tap
            u16 hv = f2bf(v[i] * d);
            int ci64 = ci & 63;
            // swizzled u16 index: co*64 + (ci64 ^ ((co&7)<<3))
            size_t base = ((size_t)(b * 9 + k9) * 2 + (ci >> 6)) * 8192;
            g_wtb[base + co * 64 + (ci64 ^ ((co & 7) << 3))] = hv;
        }
    }
}

// zero halo borders of g_xb
__global__ __launch_bounds__(256) void zero_border_kernel() {
    int b = blockIdx.x;
    uint4 z = make_uint4(0, 0, 0, 0);
    char* xbB = (char*)g_xb;
    for (int i = threadIdx.x; i < 16448; i += 256) {
        size_t pix; int k;
        if (i < 4128)       { pix = (size_t)(b * 258 + 0)   * 258 + (i >> 4);            k = i & 15; }
        else if (i < 8256)  { int j = i - 4128;  pix = (size_t)(b * 258 + 257) * 258 + (j >> 4);       k = j & 15; }
        else if (i < 12352) { int j = i - 8256;  pix = (size_t)(b * 258 + 1 + (j >> 4)) * 258 + 0;     k = j & 15; }
        else                { int j = i - 12352; pix = (size_t)(b * 258 + 1 + (j >> 4)) * 258 + 257;   k = j & 15; }
        *(uint4*)(xbB + pix * 256 + (size_t)k * 16) = z;
    }
}

// transpose+convert: x [b][ci][h][w] fp32 -> g_xb [b][h+1][w+1][ci] bf16 (swizzled)
__global__ __launch_bounds__(256) void transpose_kernel(const float* __restrict__ x) {
    __shared__ __align__(16) u16 t_lds[64 * 128];   // 16 KB, final byte image of 64 pixels
    const int chunk = blockIdx.x;        // 0..3 (64-px chunk)
    const int gy = blockIdx.y;           // 0..255
    const int b = blockIdx.z;
    const int px0 = chunk * 64;
    const int tid = threadIdx.x;
    const int l = tid & 63;              // pixel within chunk
    const int g = tid >> 6;              // 0..3
    const int key = (l + 1) & 7;         // (gx_p)&7 for this pixel
    const int px = px0 + l;

    const float* xb_ = x + (size_t)b * 128 * 65536 + (size_t)gy * 256 + px;
    char* ldsB = (char*)t_lds;

    #pragma unroll
    for (int cc = 0; cc < 4; ++cc) {
        int c = g + cc * 4;              // 16B-group 0..15 (8 ci each) — covers all 128 ci
        uint32_t dw[4];
        #pragma unroll
        for (int dgrp = 0; dgrp < 4; ++dgrp) {
            float lo = xb_[(size_t)(c * 8 + dgrp * 2) * 65536];
            float hi = xb_[(size_t)(c * 8 + dgrp * 2 + 1) * 65536];
            dw[dgrp] = (uint32_t)f2bf(lo) | ((uint32_t)f2bf(hi) << 16);
        }
        int slot = c ^ key;
        *(uint4*)(ldsB + l * 256 + slot * 16) = *(uint4*)dw;
    }
    __syncthreads();

    // write out 64 rows x 256B, fully coalesced
    char* outB = (char*)g_xb;
    #pragma unroll
    for (int it = 0; it < 4; ++it) {
        int flat = it * 256 + tid;
        int r = flat >> 4, k = flat & 15;
        size_t pix = ((size_t)(b * 258 + gy + 1)) * 258 + (px0 + r + 1);
        *(uint4*)(outB + pix * 256 + k * 16) = *(const uint4*)(ldsB + r * 256 + k * 16);
    }
}

// Implicit-GEMM conv: per block: batch b, 16x16 px tile, all 128 co. 512 threads.
__global__ __launch_bounds__(512, 2) void conv_kernel(float* __restrict__ y) {
    __shared__ __align__(16) u16 xs[18 * 18 * 128];   // [row][col][ci] 82944 B
    __shared__ __align__(16) u16 ab[2][8192];         // A double buffer, 2x16 KB

    const int b = blockIdx.y;
    const int t = blockIdx.x;                 // 0..255
    const int swzt = (t & 7) * 32 + (t >> 3); // XCD-aware swizzle (256 % 8 == 0)
    const int ty = swzt >> 4, tx = swzt & 15;
    const int y0 = ty * 16, x0 = tx * 16;
    const int tid = threadIdx.x;
    const int lane = tid & 63, wv = tid >> 6;
    const int kgrp = lane >> 4, lp = lane & 15;
    const int coBase = (wv & 1) * 64;
    const int py0w = (wv >> 1) * 4;

    const char* xbB = (const char*)g_xb;
    const char* wtbB = (const char*)(g_wtb) + (size_t)b * 294912;
    char* xsB = (char*)xs;

    // ---- prologue: issue X staging (108 insts) + A step 0 (16 insts) ----
    for (int i = wv; i < 108; i += 8) {
        int row = i / 6, sub = i - row * 6;
        size_t rb = ((size_t)(b * 258 + y0 + row) * 258 + x0) * 256;
        char* dst = xsB + row * 4608;
        if (sub < 4) glds16(xbB + rb + sub * 1024 + lane * 16, dst + sub * 1024);
        else {
            int px = 12 + sub;   // 16, 17
            glds4(xbB + rb + px * 256 + lane * 4, dst + px * 256);
        }
    }
    #pragma unroll
    for (int q = 0; q < 2; ++q) {
        int j = wv * 2 + q;
        glds16(wtbB + j * 1024 + lane * 16, (char*)ab[0] + j * 1024);
    }
    __syncthreads();

    f32x4 acc[4][4];
    #pragma unroll
    for (int mf = 0; mf < 4; ++mf)
        #pragma unroll
        for (int nf = 0; nf < 4; ++nf)
            acc[mf][nf] = (f32x4){0.f, 0.f, 0.f, 0.f};

    const int aswz = (lp & 7) << 4;
    const int abase = (coBase + lp) * 128;

    for (int s = 0; s < 18; ++s) {
        if (s < 17) {
            const char* src = wtbB + (s + 1) * 16384;
            char* dst = (char*)ab[(s + 1) & 1];
            #pragma unroll
            for (int q = 0; q < 2; ++q) {
                int j = wv * 2 + q;
                glds16(src + j * 1024 + lane * 16, dst + j * 1024);
            }
        }

        const int tap = s >> 1, chunk = s & 1;
        const int ky = tap / 3, kx = tap - ky * 3;
        const char* abuf = (const char*)ab[s & 1];
        const int ccol = lp + kx;
        const int bswz = (ccol & 7) << 4;
        const int brow0 = (py0w + ky) * 4608 + ccol * 256;
        const int cb0 = chunk * 128;

        #pragma unroll
        for (int ks = 0; ks < 2; ++ks) {
            const int ka = (ks * 64 + kgrp * 16) ^ aswz;
            const int kb = (cb0 + ks * 64 + kgrp * 16) ^ bswz;
            bf16x8 af[4];
            #pragma unroll
            for (int mf = 0; mf < 4; ++mf)
                af[mf] = *(const bf16x8*)(abuf + abase + mf * 2048 + ka);
            bf16x8 bfv[4];
            #pragma unroll
            for (int nf = 0; nf < 4; ++nf)
                bfv[nf] = *(const bf16x8*)(xsB + brow0 + nf * 4608 + kb);
            #pragma unroll
            for (int mf = 0; mf < 4; ++mf)
                #pragma unroll
                for (int nf = 0; nf < 4; ++nf)
                    acc[mf][nf] = __builtin_amdgcn_mfma_f32_16x16x32_bf16(
                        af[mf], bfv[nf], acc[mf][nf], 0, 0, 0);
        }
        __syncthreads();
    }

    // ---- epilogue ----
    float* yb = y + (size_t)b * 128 * 65536;
    #pragma unroll
    for (int mf = 0; mf < 4; ++mf) {
        #pragma unroll
        for (int nf = 0; nf < 4; ++nf) {
            int gy = y0 + py0w + nf;
            #pragma unroll
            for (int r = 0; r < 4; ++r) {
                int co = coBase + mf * 16 + kgrp * 4 + r;
                yb[(size_t)co * 65536 + gy * 256 + x0 + lp] = acc[mf][nf][r];
            }
        }
    }
}

extern "C" void kernel_launch(void* const* d_in, const int* in_sizes, int n_in,
                              void* d_out, int out_size, void* d_ws, size_t ws_size,
                              hipStream_t stream) {
    const float* x = (const float*)d_in[0];
    const float* style = (const float*)d_in[1];
    const float* w_base = (const float*)d_in[2];
    const float* aff_w = (const float*)d_in[3];
    const float* aff_b = (const float*)d_in[4];
    float* y = (float*)d_out;

    affine_kernel<<<BB, 128, 0, stream>>>(style, aff_w, aff_b);
    modulate_kernel<<<BB * 128, 256, 0, stream>>>(w_base);
    zero_border_kernel<<<BB, 256, 0, stream>>>();
    transpose_kernel<<<dim3(4, 256, BB), 256, 0, stream>>>(x);
    conv_kernel<<<dim3(256, BB), 512, 0, stream>>>(y);
}